// Round 15
// baseline (497.693 us; speedup 1.0000x reference)
//
#include <hip/hip_runtime.h>
#include <hip/hip_bf16.h>

#define BATCH 512
#define NNODE 131072
#define NEDGE 131072
#define SCAN_BLK 1024
#define SCAN_NBLK (NNODE / SCAN_BLK)   // 128
#define PCAP (8 * NEDGE)               // per-pair entry capacity (expected ~4N)

// U-layer CSR per pair (U = first-applied layer of the pair: pair0->edges3, pair1->edges1)
__device__ int g_counts[2][NNODE];
__device__ int g_offs[2][NNODE];
__device__ int g_cursor[2][NNODE];
__device__ int g_srcl[2][NEDGE];
__device__ int g_bsums[2][SCAN_NBLK];

// Pair-combined CSR: P = (I+A_V)(I+A_U) i.e. U applied first. Identity included.
__device__ int p_cnt[2][NNODE];
__device__ int p_offs[2][NNODE];
__device__ int p_cursor[2][NNODE];
__device__ int p_srcl[2][PCAP];
__device__ int p_bsums[2][SCAN_NBLK];

typedef unsigned int uivec4 __attribute__((ext_vector_type(4)));
typedef float fvec4 __attribute__((ext_vector_type(4)));

__device__ __forceinline__ void nt_store_u4(uint4* p, uint4 v) {
    uivec4 w = {v.x, v.y, v.z, v.w};
    __builtin_nontemporal_store(w, reinterpret_cast<uivec4*>(p));
}

__device__ __forceinline__ void nt_store_f4(float* p, float4 v) {
    fvec4 w = {v.x, v.y, v.z, v.w};
    __builtin_nontemporal_store(w, reinterpret_cast<fvec4*>(p));
}

// ---- U-layer CSR build ----
__global__ void zero2_k() {
    int i = blockIdx.x * blockDim.x + threadIdx.x;   // 0..2N
    ((int*)g_counts)[i] = 0;
}

__global__ void histU_k(const int* __restrict__ u0, const int* __restrict__ u1) {
    int i = blockIdx.x * blockDim.x + threadIdx.x;   // 0..2E
    int pr = i >> 17;
    int e = i & (NEDGE - 1);
    const int* eg = pr ? u1 : u0;
    atomicAdd(&g_counts[pr][eg[NEDGE + e]], 1);
}

// also initializes p_cnt[pr][i] = 1 + cU[i]
__global__ void scan_block_k() {
    __shared__ int sh[SCAN_BLK];
    int pr = blockIdx.x / SCAN_NBLK;
    int blk = blockIdx.x % SCAN_NBLK;
    int t = threadIdx.x;
    int i = blk * SCAN_BLK + t;
    int own = g_counts[pr][i];
    p_cnt[pr][i] = 1 + own;
    sh[t] = own;
    __syncthreads();
    for (int off = 1; off < SCAN_BLK; off <<= 1) {
        int v = (t >= off) ? sh[t - off] : 0;
        __syncthreads();
        sh[t] += v;
        __syncthreads();
    }
    g_offs[pr][i] = sh[t] - own;
    if (t == SCAN_BLK - 1) g_bsums[pr][blk] = sh[t];
}

__global__ void scan_bsums_k() {
    __shared__ int sh[SCAN_NBLK];
    int pr = blockIdx.x;
    int t = threadIdx.x;
    int own = g_bsums[pr][t];
    sh[t] = own;
    __syncthreads();
    for (int off = 1; off < SCAN_NBLK; off <<= 1) {
        int v = (t >= off) ? sh[t - off] : 0;
        __syncthreads();
        sh[t] += v;
        __syncthreads();
    }
    g_bsums[pr][t] = sh[t] - own;
}

__global__ void scan_add_k() {
    int pr = blockIdx.x / SCAN_NBLK;
    int blk = blockIdx.x % SCAN_NBLK;
    int i = blk * SCAN_BLK + threadIdx.x;
    int o = g_offs[pr][i] + g_bsums[pr][blk];
    g_offs[pr][i] = o;
    g_cursor[pr][i] = o;
}

__global__ void fillU_k(const int* __restrict__ u0, const int* __restrict__ u1) {
    int i = blockIdx.x * blockDim.x + threadIdx.x;   // 0..2E
    int pr = i >> 17;
    int e = i & (NEDGE - 1);
    const int* eg = pr ? u1 : u0;
    int s = eg[e];
    int d = eg[NEDGE + e];
    int p = atomicAdd(&g_cursor[pr][d], 1);
    g_srcl[pr][p] = s;
}

// ---- pair CSR, edge-centric over V edges (V = second-applied: pair0->edges2, pair1->edges0) ----
__global__ void pedge_cnt_k(const int* __restrict__ v0, const int* __restrict__ v1) {
    int i = blockIdx.x * blockDim.x + threadIdx.x;   // 0..2E
    int pr = i >> 17;
    int e = i & (NEDGE - 1);
    const int* eg = pr ? v1 : v0;
    int s = eg[e];
    int d = eg[NEDGE + e];
    atomicAdd(&p_cnt[pr][d], 1 + g_counts[pr][s]);
}

__global__ void pscan_block_k() {
    __shared__ int sh[SCAN_BLK];
    int pr = blockIdx.x / SCAN_NBLK;
    int blk = blockIdx.x % SCAN_NBLK;
    int t = threadIdx.x;
    int i = blk * SCAN_BLK + t;
    int own = p_cnt[pr][i];
    sh[t] = own;
    __syncthreads();
    for (int off = 1; off < SCAN_BLK; off <<= 1) {
        int v = (t >= off) ? sh[t - off] : 0;
        __syncthreads();
        sh[t] += v;
        __syncthreads();
    }
    p_offs[pr][i] = sh[t] - own;
    if (t == SCAN_BLK - 1) p_bsums[pr][blk] = sh[t];
}

__global__ void pscan_bsums_k() {
    __shared__ int sh[SCAN_NBLK];
    int pr = blockIdx.x;
    int t = threadIdx.x;
    int own = p_bsums[pr][t];
    sh[t] = own;
    __syncthreads();
    for (int off = 1; off < SCAN_NBLK; off <<= 1) {
        int v = (t >= off) ? sh[t - off] : 0;
        __syncthreads();
        sh[t] += v;
        __syncthreads();
    }
    p_bsums[pr][t] = sh[t] - own;
}

// finalize p_offs; cursor starts after the base segment {d} ∪ Ucol(d)
__global__ void pscan_add_k() {
    int pr = blockIdx.x / SCAN_NBLK;
    int blk = blockIdx.x % SCAN_NBLK;
    int i = blk * SCAN_BLK + threadIdx.x;
    int o = p_offs[pr][i] + p_bsums[pr][blk];
    p_offs[pr][i] = o;
    p_cursor[pr][i] = o + 1 + g_counts[pr][i];
}

// base segment: buf = {d, Ucol(d)...}
__global__ void pfill_base_k() {
    int i = blockIdx.x * blockDim.x + threadIdx.x;   // 0..2N
    int pr = i >> 17;
    int d = i & (NNODE - 1);
    int p = p_offs[pr][d];
    int* buf = p_srcl[pr];
    buf[p++] = d;
    int ub = g_offs[pr][d], ud = g_counts[pr][d];
    for (int j = 0; j < ud; ++j) buf[p++] = g_srcl[pr][ub + j];
}

// per V-edge segment: {s, Ucol(s)...}
__global__ void pfill_edge_k(const int* __restrict__ v0, const int* __restrict__ v1) {
    int i = blockIdx.x * blockDim.x + threadIdx.x;   // 0..2E
    int pr = i >> 17;
    int e = i & (NEDGE - 1);
    const int* eg = pr ? v1 : v0;
    int s = eg[e];
    int d = eg[NEDGE + e];
    int cs = g_counts[pr][s];
    int p = atomicAdd(&p_cursor[pr][d], 1 + cs);
    int* buf = p_srcl[pr];
    buf[p++] = s;
    int sb = g_offs[pr][s];
    for (int k = 0; k < cs; ++k) buf[p++] = g_srcl[pr][sb + k];
}

// ---- transpose in: x (B,N) f32 -> out (N,B) bf16. 64x64 tiles, (16,16) ----
__global__ void transpose_bf_k(const float* __restrict__ in, unsigned short* __restrict__ out) {
    __shared__ float tile[64][65];
    int c0 = blockIdx.x * 64;   // N dim
    int r0 = blockIdx.y * 64;   // B dim
    int tx = threadIdx.x;
    int ty = threadIdx.y;
    float4 v[4];
#pragma unroll
    for (int i = 0; i < 4; ++i)
        v[i] = *reinterpret_cast<const float4*>(&in[(size_t)(r0 + ty + 16 * i) * NNODE + c0 + 4 * tx]);
#pragma unroll
    for (int i = 0; i < 4; ++i) {
        tile[ty + 16 * i][4 * tx + 0] = v[i].x;
        tile[ty + 16 * i][4 * tx + 1] = v[i].y;
        tile[ty + 16 * i][4 * tx + 2] = v[i].z;
        tile[ty + 16 * i][4 * tx + 3] = v[i].w;
    }
    __syncthreads();
#pragma unroll
    for (int i = 0; i < 4; ++i) {
        int n = c0 + ty + 16 * i;
        ushort4 w;
        __hip_bfloat16 h0 = __float2bfloat16(tile[4 * tx + 0][ty + 16 * i]);
        __hip_bfloat16 h1 = __float2bfloat16(tile[4 * tx + 1][ty + 16 * i]);
        __hip_bfloat16 h2 = __float2bfloat16(tile[4 * tx + 2][ty + 16 * i]);
        __hip_bfloat16 h3 = __float2bfloat16(tile[4 * tx + 3][ty + 16 * i]);
        w.x = *reinterpret_cast<unsigned short*>(&h0);
        w.y = *reinterpret_cast<unsigned short*>(&h1);
        w.z = *reinterpret_cast<unsigned short*>(&h2);
        w.w = *reinterpret_cast<unsigned short*>(&h3);
        *reinterpret_cast<ushort4*>(&out[(size_t)n * BATCH + r0 + 4 * tx]) = w;
    }
}

// ---- transpose out: in (N,B) bf16 -> out (B,N) f32. 64x64 tiles, (16,16) ----
__global__ void transpose_fb_k(const unsigned short* __restrict__ in, float* __restrict__ out) {
    __shared__ float tile[64][65];    // [n-local][b-local]
    int n0 = blockIdx.x * 64;
    int b0 = blockIdx.y * 64;
    int tx = threadIdx.x;
    int ty = threadIdx.y;
#pragma unroll
    for (int i = 0; i < 4; ++i) {
        int nl = ty + 16 * i;
        ushort4 w = *reinterpret_cast<const ushort4*>(&in[(size_t)(n0 + nl) * BATCH + b0 + 4 * tx]);
        tile[nl][4 * tx + 0] = __uint_as_float((unsigned)w.x << 16);
        tile[nl][4 * tx + 1] = __uint_as_float((unsigned)w.y << 16);
        tile[nl][4 * tx + 2] = __uint_as_float((unsigned)w.z << 16);
        tile[nl][4 * tx + 3] = __uint_as_float((unsigned)w.w << 16);
    }
    __syncthreads();
#pragma unroll
    for (int i = 0; i < 4; ++i) {
        int bl = ty + 16 * i;
        float4 w;
        w.x = tile[4 * tx + 0][bl];
        w.y = tile[4 * tx + 1][bl];
        w.z = tile[4 * tx + 2][bl];
        w.w = tile[4 * tx + 3][bl];
        nt_store_f4(&out[(size_t)(b0 + bl) * NNODE + n0 + 4 * tx], w);
    }
}

// bf16 unpack-accumulate: uint4 = 8 bf16 -> 8 f32 adds
__device__ __forceinline__ void gacc8(float* a, uint4 v) {
    a[0] += __uint_as_float(v.x << 16);
    a[1] += __uint_as_float(v.x & 0xffff0000u);
    a[2] += __uint_as_float(v.y << 16);
    a[3] += __uint_as_float(v.y & 0xffff0000u);
    a[4] += __uint_as_float(v.z << 16);
    a[5] += __uint_as_float(v.z & 0xffff0000u);
    a[6] += __uint_as_float(v.w << 16);
    a[7] += __uint_as_float(v.w & 0xffff0000u);
}

__device__ __forceinline__ unsigned pack2(float lo, float hi) {
    __hip_bfloat16 l = __float2bfloat16(lo);
    __hip_bfloat16 h = __float2bfloat16(hi);
    return (unsigned)*reinterpret_cast<unsigned short*>(&l) |
           ((unsigned)*reinterpret_cast<unsigned short*>(&h) << 16);
}

// ---- MLP gather: each wave owns 4 consecutive nodes; 2 rounds x 4 nodes = up
// to 8 independent 1KB wave-loads in flight. 512 threads = 8 waves = 32 nodes.
// Output: 4 contiguous 1KB columns per wave, full-line NT.
__global__ void __launch_bounds__(512) gather4_k(const uint4* __restrict__ cur,
                                                 uint4* __restrict__ out, int pr) {
    int t = threadIdx.x;
    int q = t & 63;
    int wv = t >> 6;                        // 0..7
    int base = blockIdx.x * 32 + wv * 4;
    int deg[4];
    const int* sl[4];
#pragma unroll
    for (int k = 0; k < 4; ++k) {
        deg[k] = __builtin_amdgcn_readfirstlane(p_cnt[pr][base + k]);
        sl[k] = &p_srcl[pr][p_offs[pr][base + k]];
    }
    float acc[4][8];
#pragma unroll
    for (int k = 0; k < 4; ++k)
#pragma unroll
        for (int m = 0; m < 8; ++m) acc[k][m] = 0.f;
    int jmax = max(max(deg[0], deg[1]), max(deg[2], deg[3]));
    int j = 0;
    for (; j + 2 <= jmax; j += 2) {
        uint4 v[8];
#pragma unroll
        for (int k = 0; k < 4; ++k) {
            if (j < deg[k])     v[2 * k]     = cur[(size_t)sl[k][j] * 64 + q];
            if (j + 1 < deg[k]) v[2 * k + 1] = cur[(size_t)sl[k][j + 1] * 64 + q];
        }
#pragma unroll
        for (int k = 0; k < 4; ++k) {
            if (j < deg[k])     gacc8(acc[k], v[2 * k]);
            if (j + 1 < deg[k]) gacc8(acc[k], v[2 * k + 1]);
        }
    }
    if (j < jmax) {
        uint4 v[4];
#pragma unroll
        for (int k = 0; k < 4; ++k)
            if (j < deg[k]) v[k] = cur[(size_t)sl[k][j] * 64 + q];
#pragma unroll
        for (int k = 0; k < 4; ++k)
            if (j < deg[k]) gacc8(acc[k], v[k]);
    }
#pragma unroll
    for (int k = 0; k < 4; ++k) {
        uint4 w;
        w.x = pack2(acc[k][0], acc[k][1]);
        w.y = pack2(acc[k][2], acc[k][3]);
        w.z = pack2(acc[k][4], acc[k][5]);
        w.w = pack2(acc[k][6], acc[k][7]);
        nt_store_u4(&out[(size_t)(base + k) * 64 + q], w);
    }
}

extern "C" void kernel_launch(void* const* d_in, const int* in_sizes, int n_in,
                              void* d_out, int out_size, void* d_ws, size_t ws_size,
                              hipStream_t stream) {
    const float* x = (const float*)d_in[0];
    // Application order: edges3, edges2, edges1, edges0.
    // pair0 = (I+A_e2)(I+A_e3): U0 = edges3, V0 = edges2
    // pair1 = (I+A_e0)(I+A_e1): U1 = edges1, V1 = edges0
    const int* U0 = (const int*)d_in[4];   // edges3
    const int* V0 = (const int*)d_in[3];   // edges2
    const int* U1 = (const int*)d_in[2];   // edges1
    const int* V1 = (const int*)d_in[1];   // edges0

    // Two bf16 (N,B) buffers in d_ws: 128 MB each
    unsigned short* WS0 = (unsigned short*)d_ws;
    unsigned short* WS1 = WS0 + (size_t)NNODE * BATCH;
    float* OUT = (float*)d_out;

    // U-layer CSR (both pairs)
    zero2_k<<<2 * NNODE / 1024, 1024, 0, stream>>>();
    histU_k<<<2 * NEDGE / 1024, 1024, 0, stream>>>(U0, U1);
    scan_block_k<<<2 * SCAN_NBLK, SCAN_BLK, 0, stream>>>();
    scan_bsums_k<<<2, SCAN_NBLK, 0, stream>>>();
    scan_add_k<<<2 * SCAN_NBLK, SCAN_BLK, 0, stream>>>();
    fillU_k<<<2 * NEDGE / 1024, 1024, 0, stream>>>(U0, U1);

    // Pair CSR, edge-centric over V edges
    pedge_cnt_k<<<2 * NEDGE / 1024, 1024, 0, stream>>>(V0, V1);
    pscan_block_k<<<2 * SCAN_NBLK, SCAN_BLK, 0, stream>>>();
    pscan_bsums_k<<<2, SCAN_NBLK, 0, stream>>>();
    pscan_add_k<<<2 * SCAN_NBLK, SCAN_BLK, 0, stream>>>();
    pfill_base_k<<<2 * NNODE / 1024, 1024, 0, stream>>>();
    pfill_edge_k<<<2 * NEDGE / 1024, 1024, 0, stream>>>(V0, V1);

    // x (B,N) f32 -> WS0 (N,B) bf16
    transpose_bf_k<<<dim3(NNODE / 64, BATCH / 64), dim3(16, 16), 0, stream>>>(x, WS0);

    // sweep 0 (pair 0): WS0 -> WS1 (bf16, full-line NT)
    gather4_k<<<NNODE / 32, 512, 0, stream>>>((const uint4*)WS0, (uint4*)WS1, 0);
    // sweep 1 (pair 1): WS1 -> WS0 (bf16, full-line NT)
    gather4_k<<<NNODE / 32, 512, 0, stream>>>((const uint4*)WS1, (uint4*)WS0, 1);
    // transpose back: WS0 (N,B) bf16 -> d_out (B,N) f32 (full-line NT)
    transpose_fb_k<<<dim3(NNODE / 64, BATCH / 64), dim3(16, 16), 0, stream>>>(WS0, OUT);
}